// Round 9
// baseline (370.217 us; speedup 1.0000x reference)
//
#include <hip/hip_runtime.h>
#include <math.h>

// Problem constants
#define NB 2
#define SEQ 2048
#define HDIM 2048
#define NHD 16
#define NKVH 4
#define HEADD 128
#define MROWS (NB*SEQ)          // 4096
#define NQCOLS (NHD*HEADD)      // 2048
#define QKVCOLS 3072            // fused Q (2048) + K (512) + V (512)

typedef unsigned short ushortT;
typedef __attribute__((ext_vector_type(8))) short short8;
typedef __attribute__((ext_vector_type(4))) float floatx4;
typedef __attribute__((ext_vector_type(4))) unsigned short ushort4v;

__device__ __forceinline__ ushortT f2bf(float f) {
  union { float f; unsigned int u; } v; v.f = f;
  unsigned int r = v.u + 0x7FFFu + ((v.u >> 16) & 1u);
  return (ushortT)(r >> 16);
}
__device__ __forceinline__ float bf2f(ushortT u) {
  union { unsigned int u; float f; } v; v.u = ((unsigned int)u) << 16;
  return v.f;
}

// 2x f32 -> packed bf16 (RNE), single HW instruction on gfx950.
__device__ __forceinline__ unsigned int cvt_pk_bf16(float lo, float hi) {
  unsigned int r;
  asm("v_cvt_pk_bf16_f32 %0, %1, %2" : "=v"(r) : "v"(lo), "v"(hi));
  return r;
}

// async global->LDS, 16B per lane (LDS dest = wave-uniform base + lane*16).
__device__ __forceinline__ void gload16(const ushortT* g, ushortT* l) {
  __builtin_amdgcn_global_load_lds(
      (const __attribute__((address_space(1))) void*)g,
      (__attribute__((address_space(3))) void*)l, 16, 0, 0);
}

// raw barrier + compiler fences (do NOT use __syncthreads: it drains vmcnt(0))
__device__ __forceinline__ void tile_barrier() {
  asm volatile("" ::: "memory");
  __builtin_amdgcn_s_barrier();
  asm volatile("" ::: "memory");
  __builtin_amdgcn_sched_barrier(0);
}

// ---------------- cast fp32 -> bf16 (vectorized) ----------------
__global__ __launch_bounds__(256) void cast_bf16_kernel(
    const float* __restrict__ in, ushortT* __restrict__ out, int n4) {
  int i = blockIdx.x * 256 + threadIdx.x;
  if (i >= n4) return;
  float4 v = ((const float4*)in)[i];
  ushort4v o;
  o.x = f2bf(v.x); o.y = f2bf(v.y); o.z = f2bf(v.z); o.w = f2bf(v.w);
  ((ushort4v*)out)[i] = o;
}

// ------- fused transpose+cast of Wq | Wkv | Wo into Wqkvt||Wot (contiguous) ----
// unified col index cu in [0,5120): 0-2047 Wq, 2048-3071 Wkv, 3072-5119 Wo.
// out[cu*2048 + r]; all sources have R=2048 rows.
__global__ __launch_bounds__(256) void transpose_cast3_kernel(
    const float* __restrict__ Wq, const float* __restrict__ Wkv,
    const float* __restrict__ Wo, ushortT* __restrict__ out) {
  __shared__ ushortT tile[32][33];
  int cu0 = blockIdx.x * 32, r0 = blockIdx.y * 32;
  const float* src; int C, c0;
  if (cu0 < 2048)      { src = Wq;  C = 2048; c0 = cu0; }
  else if (cu0 < 3072) { src = Wkv; C = 1024; c0 = cu0 - 2048; }
  else                 { src = Wo;  C = 2048; c0 = cu0 - 3072; }
  int tx = threadIdx.x & 31, ty = threadIdx.x >> 5;  // ty 0..7
#pragma unroll
  for (int i = 0; i < 4; ++i)
    tile[ty + i*8][tx] = f2bf(src[(size_t)(r0 + ty + i*8) * C + c0 + tx]);
  __syncthreads();
#pragma unroll
  for (int i = 0; i < 4; ++i)
    out[(size_t)(cu0 + ty + i*8) * 2048 + r0 + tx] = tile[tx][ty + i*8];
}

// ---------------- GEMM, ring-buffered deep pipeline ----------------
// C(M x 256-col-tiles) = A(MxK) * Bt(NxK)^T. 8 waves (2 x 4), BK=32,
// 4-slot LDS ring (slot = K-tile & 3). While computing tile u from slot u&3,
// stage tile u+3 into slot (u+3)&3 -- race-free by construction.
// Counted vmcnt keeps tiles u+1,u+2 in flight (never drain to 0 mid-loop).
// MH=2: BM=256 (QKV, 192 blocks). MH=1: BM=128 (proj, 256 blocks = full fill).
template <int MH>
__global__ __launch_bounds__(512, 2) void gemm_ring_kernel(
    const ushortT* __restrict__ A, const ushortT* __restrict__ Bt,
    void* __restrict__ C, int M, int N, int K, int c_fp32) {
  constexpr int BM = 128 * MH;
  __shared__ __align__(16) ushortT lA[4][BM * 32];
  __shared__ __align__(16) ushortT lB[4][256 * 32];
  const int m0 = blockIdx.y * BM;
  const int n0 = blockIdx.x * 256;
  const int tid = threadIdx.x;
  const int lane = tid & 63, wave = tid >> 6;
  const int g = lane >> 4, l15 = lane & 15;
  const int wr = wave >> 2, wc = wave & 3;       // wave grid 2 x 4
  const int wm = wr * (BM / 2), wn = wc * 64;

  floatx4 acc[4 * MH][4] = {};

  auto stageA = [&](int u) {           // A of K-tile u -> slot u&3
    ushortT* dst = lA[u & 3];
    const int kt = u << 5;
#pragma unroll
    for (int i = 0; i < MH; ++i) {
      int s = i * 512 + tid;           // 16B chunk id
      int r = s >> 2, j = s & 3;
      int jj = j ^ ((r >> 1) & 3);     // inverse-swizzled source granule
      gload16(A + (size_t)(m0 + r) * K + kt + jj * 8, dst + s * 8);
    }
  };
  auto stageB = [&](int u) {
    ushortT* dst = lB[u & 3];
    const int kt = u << 5;
#pragma unroll
    for (int i = 0; i < 2; ++i) {
      int s = i * 512 + tid;
      int r = s >> 2, j = s & 3;
      int jj = j ^ ((r >> 1) & 3);
      gload16(Bt + (size_t)(n0 + r) * K + kt + jj * 8, dst + s * 8);
    }
  };

  // prologue: stage K-tiles 0,1,2 (NT >= 4 always here: K >= 2048)
  stageA(0); stageB(0); stageA(1); stageB(1); stageA(2); stageB(2);

  const int NT = K >> 5;
  for (int u = 0; u < NT; ++u) {
    // wait for tile u's stages; keep tiles u+1, u+2 outstanding (counted vmcnt)
    if constexpr (MH == 2) {
      if (u + 2 < NT)      asm volatile("s_waitcnt vmcnt(8)" ::: "memory");
      else if (u + 1 < NT) asm volatile("s_waitcnt vmcnt(4)" ::: "memory");
      else                 asm volatile("s_waitcnt vmcnt(0)" ::: "memory");
    } else {
      if (u + 2 < NT)      asm volatile("s_waitcnt vmcnt(6)" ::: "memory");
      else if (u + 1 < NT) asm volatile("s_waitcnt vmcnt(3)" ::: "memory");
      else                 asm volatile("s_waitcnt vmcnt(0)" ::: "memory");
    }
    tile_barrier();                    // all waves' tile-u loads landed

    const ushortT* la = lA[u & 3];
    const ushortT* lb = lB[u & 3];
    const bool more = (u + 3) < NT;

    // B fragments once per K-tile (reused across m-phases)
    short8 bfr[4];
#pragma unroll
    for (int nt = 0; nt < 4; ++nt) {
      int col = wn + nt * 16 + l15;
      bfr[nt] = *(const short8*)(lb + col * 32 + (g ^ ((col >> 1) & 3)) * 8);
    }

#pragma unroll
    for (int mh = 0; mh < MH; ++mh) {  // no mid-tile barrier (slot liveness)
      short8 afr[4];
#pragma unroll
      for (int mt = 0; mt < 4; ++mt) {
        int row = wm + mh * 64 + mt * 16 + l15;
        afr[mt] = *(const short8*)(la + row * 32 + (g ^ ((row >> 1) & 3)) * 8);
      }
      if (more) {                      // spread prefetch of tile u+3
        if (mh == 0) stageA(u + 3);
        if (mh == MH - 1) stageB(u + 3);
      }
      __builtin_amdgcn_s_setprio(1);
#pragma unroll
      for (int mt = 0; mt < 4; ++mt)
#pragma unroll
        for (int nt = 0; nt < 4; ++nt)
          acc[mh * 4 + mt][nt] = __builtin_amdgcn_mfma_f32_16x16x32_bf16(
              afr[mt], bfr[nt], acc[mh * 4 + mt][nt], 0, 0, 0);
      __builtin_amdgcn_s_setprio(0);
    }
  }

  // epilogue: row = m0+wm+fm*16+g*4+r, col = n0+wn+nt*16+l15
#pragma unroll
  for (int fm = 0; fm < 4 * MH; ++fm)
#pragma unroll
    for (int nt = 0; nt < 4; ++nt)
#pragma unroll
      for (int r4 = 0; r4 < 4; ++r4) {
        int row = m0 + wm + fm * 16 + g * 4 + r4;
        int col = n0 + wn + nt * 16 + l15;
        float v = acc[fm][nt][r4];
        if (c_fp32) ((float*)C)[(size_t)row * N + col] = v;
        else ((ushortT*)C)[(size_t)row * N + col] = f2bf(v);
      }
}

// ---------------- fused RoPE Q+K: QKVtmp -> Qr (B,NH,S,HD), Kr (B,NKV,S,HD) ----
__global__ __launch_bounds__(256) void rope_qk_kernel(
    const ushortT* __restrict__ QKVtmp, const float* __restrict__ cosT,
    const float* __restrict__ sinT, ushortT* __restrict__ Qr,
    ushortT* __restrict__ Kr) {
  int idx = blockIdx.x * 256 + threadIdx.x;
  if (idx < NB * SEQ * NHD * 64) {               // Q part (blocks 0..16383)
    int d = idx & 63;
    int t = idx >> 6;          // (b*S+s)*NH + h
    int h = t & (NHD - 1);
    int bs = t >> 4;
    int s = bs & (SEQ - 1);
    int b = bs >> 11;
    float c = cosT[s * HEADD + d], sn = sinT[s * HEADD + d];
    float q1 = bf2f(QKVtmp[(size_t)bs * QKVCOLS + h * HEADD + d]);
    float q2 = bf2f(QKVtmp[(size_t)bs * QKVCOLS + h * HEADD + d + 64]);
    size_t o = ((size_t)(b * NHD + h) * SEQ + s) * HEADD + d;
    Qr[o]      = f2bf(q1 * c - q2 * sn);
    Qr[o + 64] = f2bf(q2 * c + q1 * sn);
  } else {                                       // K part (blocks 16384..20479)
    int k = idx - NB * SEQ * NHD * 64;
    int d = k & 63;
    int t = k >> 6;            // (b*S+s)*NKV + kvh
    int kvh = t & (NKVH - 1);
    int bs = t >> 2;
    int s = bs & (SEQ - 1);
    int b = bs >> 11;
    float c = cosT[s * HEADD + d], sn = sinT[s * HEADD + d];
    float k1 = bf2f(QKVtmp[(size_t)bs * QKVCOLS + 2048 + kvh * HEADD + d]);
    float k2 = bf2f(QKVtmp[(size_t)bs * QKVCOLS + 2048 + kvh * HEADD + d + 64]);
    size_t o = ((size_t)(b * NKVH + kvh) * SEQ + s) * HEADD + d;
    Kr[o]      = f2bf(k1 * c - k2 * sn);
    Kr[o + 64] = f2bf(k2 * c + k1 * sn);
  }
}

// ---------------- V relayout: QKVtmp cols [2560,3072) -> (B,NKV,HD,S) ----------
__global__ __launch_bounds__(256) void v_relayout_kernel(
    const ushortT* __restrict__ QKVtmp, ushortT* __restrict__ Vt) {
  __shared__ ushortT tile[32][33];
  int bk = blockIdx.z;             // b*NKV + kvh
  int b = bk >> 2, kvh = bk & 3;
  int s0 = blockIdx.x * 32, d0 = blockIdx.y * 32;
  int tx = threadIdx.x & 31, ty = threadIdx.x >> 5;
#pragma unroll
  for (int i = 0; i < 4; ++i) {
    int s = s0 + ty + i * 8;
    tile[ty + i * 8][tx] =
        QKVtmp[(size_t)(b * SEQ + s) * QKVCOLS + 2560 + kvh * HEADD + d0 + tx];
  }
  __syncthreads();
#pragma unroll
  for (int i = 0; i < 4; ++i) {
    int d = d0 + ty + i * 8;
    Vt[((size_t)bk * HEADD + d) * SEQ + s0 + tx] = tile[tx][ty + i * 8];
  }
}

// ---------------- Flash attention (causal, GQA), BM=64 / BN=64 -----------------
// R8 structure + FUSED k-loop: block owns q-tiles {31-yi, yi}, but instead of
// two sequential phases it runs ONE k-loop (kt = 0..31-yi). The long q-tile is
// computed every iteration; the short one while kt <= yi -- so k-tiles 0..yi
// are staged and LDS-read ONCE instead of twice. Total computes stay 33/block
// (balance preserved); stage+read passes drop 33 -> 32-yi (avg 24.5, -26%).
// Two separately-named state sets (oA/oB -- no runtime-indexed arrays).
// P-LDS is reused A-then-B within an iteration: per-wave DS FIFO is in-order,
// so PV-A's reads retire before B's writes. 512 blocks, 72 KiB, 2/CU.
__global__ __launch_bounds__(256) void attn_kernel(
    const ushortT* __restrict__ Q,   // (B,NH,S,HD)
    const ushortT* __restrict__ Kg,  // (B,NKV,S,HD)
    const ushortT* __restrict__ Vg,  // (B,NKV,HD,S)
    ushortT* __restrict__ Oa) {      // (B,S,NH*HD)
  __shared__ __align__(16) ushortT lK[2][64 * 128];  // key x d, swizzled (2 buf)
  __shared__ __align__(16) ushortT lV[2][128 * 64];  // d x key, swizzled (2 buf)
  __shared__ __align__(16) ushortT lP[4 * 16 * 64];  // per-wave P, 16B-XOR swz

  const int tid = threadIdx.x;
  const int w = tid >> 6, lane = tid & 63;
  const int g = lane >> 4, l15 = lane & 15;
  const int sw = l15 & 7;
  const int bh = blockIdx.x;
  const int b = bh >> 4, h = bh & 15;
  const int kvh = h >> 2;
  const int yi = blockIdx.y;          // 0..15
  const int qiA = 31 - yi;            // long q-tile: nA = 32-yi k-tiles
  const int qiB = yi;                 // short q-tile: nB = yi+1 k-tiles
  const int nA = qiA + 1, nB = qiB + 1;   // computes nA+nB == 33 per block

  const float SC = 0.08838834764831845f * 1.4426950408889634f; // 1/sqrt(128)*log2e
  const float THR = 8.0f / SC;        // defer-max threshold in raw-score units

  const ushortT* kbase = Kg + ((size_t)(b * NKVH + kvh)) * SEQ * HEADD;
  const ushortT* vbase = Vg + ((size_t)(b * NKVH + kvh)) * HEADD * SEQ;
  ushortT* pw = lP + w * 16 * 64;

  const int qwA = (qiA << 6) + w * 16;
  const int qwB = (qiB << 6) + w * 16;

  // Q fragments for both q-tiles, loaded up front (latency overlaps prologue)
  short8 qfA[4], qfB[4];
  {
    const ushortT* qpA = Q + (((size_t)(b * NHD + h)) * SEQ + qwA + l15) * HEADD + g * 8;
    const ushortT* qpB = Q + (((size_t)(b * NHD + h)) * SEQ + qwB + l15) * HEADD + g * 8;
#pragma unroll
    for (int ks = 0; ks < 4; ++ks) {
      qfA[ks] = *(const short8*)(qpA + ks * 32);
      qfB[ks] = *(const short8*)(qpB + ks * 32);
    }
  }

  floatx4 oA[8] = {}, oB[8] = {};     // O^T: col=q(l15), row=d(g*4+r)
  float m_sA = -INFINITY, m_sB = -INFINITY;  // running max (RAW score units)
  float l_sA = 0.f, l_sB = 0.f;

  auto stage = [&](int kt, int buf) {
#pragma unroll
    for (int ii = 0; ii < 4; ++ii) {          // K tile: 64 keys x 128 d
      int s = ii * 256 + tid;
      int r = s >> 4, j = (s & 15) ^ (r & 7);
      gload16(kbase + (size_t)(kt * 64 + r) * HEADD + j * 8, lK[buf] + s * 8);
    }
#pragma unroll
    for (int ii = 0; ii < 4; ++ii) {          // V^T tile: 128 d x 64 keys
      int s = ii * 256 + tid;
      int r = s >> 3, j = (s & 7) ^ (r & 7);
      gload16(vbase + (size_t)r * SEQ + kt * 64 + j * 8, lV[buf] + s * 8);
    }
  };

  auto compute = [&](const short8 (&qf)[4], int qw, int kt, int cur,
                     floatx4 (&o)[8], float& m_s, float& l_s) {
    const int rel = qw - kt * 64;   // >= 0; < 64 only on the diagonal tile

    // S^T = K · Q^T : D col = q (l15), row = key (g*4+r), per nt key-16-block
    floatx4 sc4[4] = {};
    __builtin_amdgcn_s_setprio(1);
#pragma unroll
    for (int nt = 0; nt < 4; ++nt) {
      if (nt * 16 > rel + 15) continue;       // fully-masked key block (uniform)
#pragma unroll
      for (int ks = 0; ks < 4; ++ks) {
        short8 kf = *(const short8*)(lK[cur] + (nt * 16 + l15) * 128 + ((ks * 4 + g) ^ sw) * 8);
        sc4[nt] = __builtin_amdgcn_mfma_f32_16x16x32_bf16(kf, qf[ks], sc4[nt], 0, 0, 0);
      }
    }
    __builtin_amdgcn_s_setprio(0);

    const bool needmask = (kt * 64 + 63) > qw;  // wave-uniform
    float ps[4][4];
    float mx = -INFINITY;
#pragma unroll
    for (int nt = 0; nt < 4; ++nt)
#pragma unroll
      for (int r = 0; r < 4; ++r) {
        float v = sc4[nt][r];                 // RAW score (SC folded into exp)
        if (needmask) {
          int kg = kt * 64 + nt * 16 + g * 4 + r;
          if (kg > qw + l15) v = -INFINITY;
        }
        ps[nt][r] = v;
        mx = fmaxf(mx, v);
      }
    mx = fmaxf(mx, __shfl_xor(mx, 16));
    mx = fmaxf(mx, __shfl_xor(mx, 32));

    // defer-max: only rescale O when some row's max grew by > THR (rare)
    float mn;
    if (__all(mx <= m_s + THR)) {
      mn = m_s;
    } else {
      mn = fmaxf(m_s, mx);
      float alpha = __builtin_amdgcn_exp2f((m_s - mn) * SC);
      l_s *= alpha;
#pragma unroll
      for (int dt = 0; dt < 8; ++dt)
#pragma unroll
        for (int r = 0; r < 4; ++r) o[dt][r] *= alpha;
      m_s = mn;
    }
    const float mnSC = mn * SC;

    float rs = 0.f;
#pragma unroll
    for (int nt = 0; nt < 4; ++nt) {
      float e[4];
#pragma unroll
      for (int r = 0; r < 4; ++r) {
        e[r] = __builtin_amdgcn_exp2f(__builtin_fmaf(ps[nt][r], SC, -mnSC));
        rs += e[r];
      }
      uint2 pk;
      pk.x = cvt_pk_bf16(e[0], e[1]);
      pk.y = cvt_pk_bf16(e[2], e[3]);
      // row l15 (64 ushorts); 16B-granule (nt*2+(g>>1)) XOR-swizzled by l15&7
      *(uint2*)(pw + l15 * 64 + (((nt * 2 + (g >> 1)) ^ sw) * 8 + (g & 1) * 4)) = pk;
    }
    rs += __shfl_xor(rs, 16);
    rs += __shfl_xor(rs, 32);
    l_s += rs;

    // O^T += V^T · P^T   (A = V^T frag from lV, B = P^T frag from lP)
    __builtin_amdgcn_s_setprio(1);
#pragma unroll
    for (int ks = 0; ks < 2; ++ks) {
      if (kt * 64 + ks * 32 > qw + 15) continue;  // fully-masked (uniform)
      short8 bp = *(const short8*)(pw + l15 * 64 + ((ks * 4 + g) ^ sw) * 8);
#pragma unroll
      for (int dt = 0; dt < 8; ++dt) {
        short8 vf = *(const short8*)(lV[cur] + (dt * 16 + l15) * 64 + ((ks * 4 + g) ^ sw) * 8);
        o[dt] = __builtin_amdgcn_mfma_f32_16x16x32_bf16(vf, bp, o[dt], 0, 0, 0);
      }
    }
    __builtin_amdgcn_s_setprio(0);
  };

  auto epilogue = [&](int qw, floatx4 (&o)[8], float l_s) {
    float inv = 1.f / l_s;
    int qg = qw + l15;
#pragma unroll
    for (int dt = 0; dt < 8; ++dt) {
      uint2 ov;
      ov.x = cvt_pk_bf16(o[dt][0] * inv, o[dt][1] * inv);
      ov.y = cvt_pk_bf16(o[dt][2] * inv, o[dt][3] * inv);
      *(uint2*)(Oa + (size_t)(b * SEQ + qg) * NQCOLS + h * HEADD + dt * 16 + g * 4) = ov;
    }
  };

  // ---- pipeline prologue ----
  stage(0, 0);
  asm volatile("s_waitcnt vmcnt(0)" ::: "memory");
  __builtin_amdgcn_s_barrier();

  // ---- fused k-loop: long q-tile always; short q-tile while kt < nB ----
  for (int kt = 0; kt < nA; ++kt) {
    const int cur = kt & 1;
    if (kt + 1 < nA) stage(kt + 1, cur ^ 1);
    compute(qfA, qwA, kt, cur, oA, m_sA, l_sA);
    if (kt < nB) compute(qfB, qwB, kt, cur, oB, m_sB, l_sB);
    asm volatile("s_waitcnt vmcnt(0)" ::: "memory");
    __builtin_amdgcn_s_barrier();
  }
  epilogue(qwA, oA, l_sA);
  epilogue(qwB, oB, l_sB);
}

extern "C" void kernel_launch(void* const* d_in, const int* in_sizes, int n_in,
                              void* d_out, int out_size, void* d_ws, size_t ws_size,
                              hipStream_t stream) {
  const float* x    = (const float*)d_in[0];
  const float* cosT = (const float*)d_in[1];
  const float* sinT = (const float*)d_in[2];
  const float* Wq   = (const float*)d_in[3];
  const float* Wkv  = (const float*)d_in[4];
  const float* Wo   = (const float*)d_in[5];

  char* ws = (char*)d_ws;
  // workspace layout (bytes)
  ushortT* x_bf   = (ushortT*)(ws + 0);          // 16777216
  ushortT* Wqkvt  = (ushortT*)(ws + 16777216);   // 12582912 (3072 x 2048 bf16)
  ushortT* Wot    = (ushortT*)(ws + 29360128);   //  8388608 (contiguous w/ Wqkvt)
  ushortT* QKVtmp = (ushortT*)(ws + 37748736);   // 25165824 (4096 x 3072 bf16)
  ushortT* Qr     = (ushortT*)(ws + 62914560);   // 16777216
  ushortT* Kr     = (ushortT*)(ws + 79691776);   //  4194304
  ushortT* Vt     = (ushortT*)(ws + 83886080);   //  4194304
  ushortT* Oattn  = QKVtmp;                      // alias; total 88080384

  // 1) cast + fused weight transposes (Wq|Wkv|Wo -> Wqkvt||Wot, one launch)
  cast_bf16_kernel<<<8192, 256, 0, stream>>>(x, x_bf, (MROWS * HDIM) / 4);
  transpose_cast3_kernel<<<dim3(160, 64), 256, 0, stream>>>(Wq, Wkv, Wo, Wqkvt);

  // 2) fused QKV projection: 256^2 ring-pipelined tiles, 192 blocks
  gemm_ring_kernel<2><<<dim3(12, 16), 512, 0, stream>>>(x_bf, Wqkvt, QKVtmp,
                                                        MROWS, QKVCOLS, HDIM, 0);

  // 3) fused rope Q+K, then V relayout
  rope_qk_kernel<<<20480, 256, 0, stream>>>(QKVtmp, cosT, sinT, Qr, Kr);
  v_relayout_kernel<<<dim3(64, 4, 8), 256, 0, stream>>>(QKVtmp, Vt);

  // 4) attention: 512 blocks, paired q-tiles over ONE fused k-loop
  //    (shared k-tiles staged+read once; 33 computes/block preserved)
  attn_kernel<<<dim3(32, 16), 256, 0, stream>>>(Qr, Kr, Vt, Oattn);

  // 5) output projection: 128x256 ring-pipelined tiles, 256 blocks (full fill)
  gemm_ring_kernel<1><<<dim3(8, 32), 512, 0, stream>>>(Oattn, Wot, d_out,
                                                       MROWS, HDIM, NQCOLS, 1);
}

// Round 10
// 310.719 us; speedup vs baseline: 1.1915x; 1.1915x over previous
//
#include <hip/hip_runtime.h>
#include <math.h>

// Problem constants
#define NB 2
#define SEQ 2048
#define HDIM 2048
#define NHD 16
#define NKVH 4
#define HEADD 128
#define MROWS (NB*SEQ)          // 4096
#define NQCOLS (NHD*HEADD)      // 2048
#define QKVCOLS 3072            // fused Q (2048) + K (512) + V (512)

typedef unsigned short ushortT;
typedef __attribute__((ext_vector_type(8))) short short8;
typedef __attribute__((ext_vector_type(4))) float floatx4;
typedef __attribute__((ext_vector_type(4))) unsigned short ushort4v;

__device__ __forceinline__ ushortT f2bf(float f) {
  union { float f; unsigned int u; } v; v.f = f;
  unsigned int r = v.u + 0x7FFFu + ((v.u >> 16) & 1u);
  return (ushortT)(r >> 16);
}
__device__ __forceinline__ float bf2f(ushortT u) {
  union { unsigned int u; float f; } v; v.u = ((unsigned int)u) << 16;
  return v.f;
}

// 2x f32 -> packed bf16 (RNE), single HW instruction on gfx950.
__device__ __forceinline__ unsigned int cvt_pk_bf16(float lo, float hi) {
  unsigned int r;
  asm("v_cvt_pk_bf16_f32 %0, %1, %2" : "=v"(r) : "v"(lo), "v"(hi));
  return r;
}

// async global->LDS, 16B per lane (LDS dest = wave-uniform base + lane*16).
__device__ __forceinline__ void gload16(const ushortT* g, ushortT* l) {
  __builtin_amdgcn_global_load_lds(
      (const __attribute__((address_space(1))) void*)g,
      (__attribute__((address_space(3))) void*)l, 16, 0, 0);
}

// raw barrier + compiler fences (do NOT use __syncthreads: it drains vmcnt(0))
__device__ __forceinline__ void tile_barrier() {
  asm volatile("" ::: "memory");
  __builtin_amdgcn_s_barrier();
  asm volatile("" ::: "memory");
  __builtin_amdgcn_sched_barrier(0);
}

// ---------------- cast fp32 -> bf16 (vectorized) ----------------
__global__ __launch_bounds__(256) void cast_bf16_kernel(
    const float* __restrict__ in, ushortT* __restrict__ out, int n4) {
  int i = blockIdx.x * 256 + threadIdx.x;
  if (i >= n4) return;
  float4 v = ((const float4*)in)[i];
  ushort4v o;
  o.x = f2bf(v.x); o.y = f2bf(v.y); o.z = f2bf(v.z); o.w = f2bf(v.w);
  ((ushort4v*)out)[i] = o;
}

// ------- fused transpose+cast of Wq | Wkv | Wo into Wqkvt||Wot (contiguous) ----
__global__ __launch_bounds__(256) void transpose_cast3_kernel(
    const float* __restrict__ Wq, const float* __restrict__ Wkv,
    const float* __restrict__ Wo, ushortT* __restrict__ out) {
  __shared__ ushortT tile[32][33];
  int cu0 = blockIdx.x * 32, r0 = blockIdx.y * 32;
  const float* src; int C, c0;
  if (cu0 < 2048)      { src = Wq;  C = 2048; c0 = cu0; }
  else if (cu0 < 3072) { src = Wkv; C = 1024; c0 = cu0 - 2048; }
  else                 { src = Wo;  C = 2048; c0 = cu0 - 3072; }
  int tx = threadIdx.x & 31, ty = threadIdx.x >> 5;  // ty 0..7
#pragma unroll
  for (int i = 0; i < 4; ++i)
    tile[ty + i*8][tx] = f2bf(src[(size_t)(r0 + ty + i*8) * C + c0 + tx]);
  __syncthreads();
#pragma unroll
  for (int i = 0; i < 4; ++i)
    out[(size_t)(cu0 + ty + i*8) * 2048 + r0 + tx] = tile[tx][ty + i*8];
}

// ---------------- GEMM 128x128, 3-slot ring, 3 blocks/CU ----------------
// C(MxN) = A(MxK)*Bt(NxK)^T. 4 waves (2x2 of 64x64), BK=32.
// LDS = 3 x (8KB A + 8KB B) = 48 KB -> 3 blocks/CU (12 waves, 3/SIMD).
// Ring: while computing tile u (slot u%3), tiles u+1,u+2 are in flight;
// stage(u+2) overwrites slot (u+2)%3 = (u-1)%3 whose last ds_reads retired
// before this tile's barrier (their MFMAs consumed them) => race-free.
// Counted vmcnt(4) waits only tile u's 4 loads (never drains mid-loop).
// QKV: grid 24x32 = 768 blocks = EXACT 3/CU one-round fill.
// proj: grid 16x32 = 512 blocks = 2/CU even.
__global__ __launch_bounds__(256, 3) void gemm_ring128_kernel(
    const ushortT* __restrict__ A, const ushortT* __restrict__ Bt,
    void* __restrict__ C, int M, int N, int K, int c_fp32) {
  __shared__ __align__(16) ushortT lA[3][128 * 32];
  __shared__ __align__(16) ushortT lB[3][128 * 32];
  const int m0 = blockIdx.y * 128;
  const int n0 = blockIdx.x * 128;
  const int tid = threadIdx.x;
  const int lane = tid & 63, wave = tid >> 6;
  const int g = lane >> 4, l15 = lane & 15;
  const int wm = (wave >> 1) * 64, wn = (wave & 1) * 64;

  floatx4 acc[4][4] = {};

  auto stage = [&](int u) {            // K-tile u -> slot u%3 (A and B)
    ushortT* dA = lA[u % 3];
    ushortT* dB = lB[u % 3];
    const int kt = u << 5;
#pragma unroll
    for (int i = 0; i < 2; ++i) {
      int s = i * 256 + tid;           // 16B chunk id, 0..511
      int r = s >> 2, j = s & 3;       // row 0..127, granule 0..3
      int jj = j ^ ((r >> 1) & 3);     // inverse-swizzled source granule
      gload16(A  + (size_t)(m0 + r) * K + kt + jj * 8, dA + s * 8);
      gload16(Bt + (size_t)(n0 + r) * K + kt + jj * 8, dB + s * 8);
    }
  };

  // prologue: tiles 0,1 in flight (NT = K/32 >= 64 here)
  stage(0); stage(1);

  const int NT = K >> 5;
  for (int u = 0; u < NT; ++u) {
    if (u + 1 < NT) asm volatile("s_waitcnt vmcnt(4)" ::: "memory"); // tile u landed
    else            asm volatile("s_waitcnt vmcnt(0)" ::: "memory");
    tile_barrier();

    const ushortT* la = lA[u % 3];
    const ushortT* lb = lB[u % 3];

    short8 afr[4], bfr[4];
#pragma unroll
    for (int t = 0; t < 4; ++t) {
      int row = wm + t * 16 + l15;
      afr[t] = *(const short8*)(la + row * 32 + (g ^ ((row >> 1) & 3)) * 8);
      int col = wn + t * 16 + l15;
      bfr[t] = *(const short8*)(lb + col * 32 + (g ^ ((col >> 1) & 3)) * 8);
    }
    if (u + 2 < NT) stage(u + 2);      // prefetch into dead slot

    __builtin_amdgcn_s_setprio(1);
#pragma unroll
    for (int mt = 0; mt < 4; ++mt)
#pragma unroll
      for (int nt = 0; nt < 4; ++nt)
        acc[mt][nt] = __builtin_amdgcn_mfma_f32_16x16x32_bf16(
            afr[mt], bfr[nt], acc[mt][nt], 0, 0, 0);
    __builtin_amdgcn_s_setprio(0);
  }

  // epilogue: row = m0+wm+mt*16+g*4+r, col = n0+wn+nt*16+l15
#pragma unroll
  for (int mt = 0; mt < 4; ++mt)
#pragma unroll
    for (int nt = 0; nt < 4; ++nt)
#pragma unroll
      for (int r4 = 0; r4 < 4; ++r4) {
        int row = m0 + wm + mt * 16 + g * 4 + r4;
        int col = n0 + wn + nt * 16 + l15;
        float v = acc[mt][nt][r4];
        if (c_fp32) ((float*)C)[(size_t)row * N + col] = v;
        else ((ushortT*)C)[(size_t)row * N + col] = f2bf(v);
      }
}

// ---------------- fused RoPE Q+K: QKVtmp -> Qr (B,NH,S,HD), Kr (B,NKV,S,HD) ----
__global__ __launch_bounds__(256) void rope_qk_kernel(
    const ushortT* __restrict__ QKVtmp, const float* __restrict__ cosT,
    const float* __restrict__ sinT, ushortT* __restrict__ Qr,
    ushortT* __restrict__ Kr) {
  int idx = blockIdx.x * 256 + threadIdx.x;
  if (idx < NB * SEQ * NHD * 64) {               // Q part (blocks 0..16383)
    int d = idx & 63;
    int t = idx >> 6;          // (b*S+s)*NH + h
    int h = t & (NHD - 1);
    int bs = t >> 4;
    int s = bs & (SEQ - 1);
    int b = bs >> 11;
    float c = cosT[s * HEADD + d], sn = sinT[s * HEADD + d];
    float q1 = bf2f(QKVtmp[(size_t)bs * QKVCOLS + h * HEADD + d]);
    float q2 = bf2f(QKVtmp[(size_t)bs * QKVCOLS + h * HEADD + d + 64]);
    size_t o = ((size_t)(b * NHD + h) * SEQ + s) * HEADD + d;
    Qr[o]      = f2bf(q1 * c - q2 * sn);
    Qr[o + 64] = f2bf(q2 * c + q1 * sn);
  } else {                                       // K part (blocks 16384..20479)
    int k = idx - NB * SEQ * NHD * 64;
    int d = k & 63;
    int t = k >> 6;            // (b*S+s)*NKV + kvh
    int kvh = t & (NKVH - 1);
    int bs = t >> 2;
    int s = bs & (SEQ - 1);
    int b = bs >> 11;
    float c = cosT[s * HEADD + d], sn = sinT[s * HEADD + d];
    float k1 = bf2f(QKVtmp[(size_t)bs * QKVCOLS + 2048 + kvh * HEADD + d]);
    float k2 = bf2f(QKVtmp[(size_t)bs * QKVCOLS + 2048 + kvh * HEADD + d + 64]);
    size_t o = ((size_t)(b * NKVH + kvh) * SEQ + s) * HEADD + d;
    Kr[o]      = f2bf(k1 * c - k2 * sn);
    Kr[o + 64] = f2bf(k2 * c + k1 * sn);
  }
}

// ---------------- V relayout: QKVtmp cols [2560,3072) -> (B,NKV,HD,S) ----------
__global__ __launch_bounds__(256) void v_relayout_kernel(
    const ushortT* __restrict__ QKVtmp, ushortT* __restrict__ Vt) {
  __shared__ ushortT tile[32][33];
  int bk = blockIdx.z;             // b*NKV + kvh
  int b = bk >> 2, kvh = bk & 3;
  int s0 = blockIdx.x * 32, d0 = blockIdx.y * 32;
  int tx = threadIdx.x & 31, ty = threadIdx.x >> 5;
#pragma unroll
  for (int i = 0; i < 4; ++i) {
    int s = s0 + ty + i * 8;
    tile[ty + i * 8][tx] =
        QKVtmp[(size_t)(b * SEQ + s) * QKVCOLS + 2560 + kvh * HEADD + d0 + tx];
  }
  __syncthreads();
#pragma unroll
  for (int i = 0; i < 4; ++i) {
    int d = d0 + ty + i * 8;
    Vt[((size_t)bk * HEADD + d) * SEQ + s0 + tx] = tile[tx][ty + i * 8];
  }
}

// ---------------- Flash attention (causal, GQA), BM=64 / BN=64 -----------------
// Proven-best structure (R5/R8: 86.4-86.7 us), restored EXACTLY. grid
// (32=bh fast, 16=pair). Each block: TWO q-tiles {31-yi, yi} -> constant 33
// k-tiles (balance; 512 blocks = 2/CU at 72 KiB). K/V double-buffered 2-phase
// pipeline: stage(t+1) -> compute(t) -> vmcnt(0) -> barrier.
// S^T = K·Q^T; O^T = V^T·P^T.
__global__ __launch_bounds__(256) void attn_kernel(
    const ushortT* __restrict__ Q,   // (B,NH,S,HD)
    const ushortT* __restrict__ Kg,  // (B,NKV,S,HD)
    const ushortT* __restrict__ Vg,  // (B,NKV,HD,S)
    ushortT* __restrict__ Oa) {      // (B,S,NH*HD)
  __shared__ __align__(16) ushortT lK[2][64 * 128];  // key x d, swizzled (2 buf)
  __shared__ __align__(16) ushortT lV[2][128 * 64];  // d x key, swizzled (2 buf)
  __shared__ __align__(16) ushortT lP[4 * 16 * 64];  // per-wave P, 16B-XOR swz

  const int tid = threadIdx.x;
  const int w = tid >> 6, lane = tid & 63;
  const int g = lane >> 4, l15 = lane & 15;
  const int sw = l15 & 7;
  const int bh = blockIdx.x;
  const int b = bh >> 4, h = bh & 15;
  const int kvh = h >> 2;
  const int yi = blockIdx.y;          // 0..15
  const int qiA = 31 - yi;            // long q-tile (32-yi k-tiles)
  const int qiB = yi;                 // short q-tile (yi+1 k-tiles)
  const int nA = qiA + 1, nB = qiB + 1;   // nA+nB == 33 for every block

  const float SC = 0.08838834764831845f * 1.4426950408889634f; // 1/sqrt(128)*log2e
  const float THR = 8.0f / SC;        // defer-max threshold in raw-score units

  const ushortT* kbase = Kg + ((size_t)(b * NKVH + kvh)) * SEQ * HEADD;
  const ushortT* vbase = Vg + ((size_t)(b * NKVH + kvh)) * HEADD * SEQ;
  ushortT* pw = lP + w * 16 * 64;

  const int qwA = (qiA << 6) + w * 16;
  const int qwB = (qiB << 6) + w * 16;

  // Q fragments for both q-tiles, loaded up front (latency overlaps prologue)
  short8 qfA[4], qfB[4];
  {
    const ushortT* qpA = Q + (((size_t)(b * NHD + h)) * SEQ + qwA + l15) * HEADD + g * 8;
    const ushortT* qpB = Q + (((size_t)(b * NHD + h)) * SEQ + qwB + l15) * HEADD + g * 8;
#pragma unroll
    for (int ks = 0; ks < 4; ++ks) {
      qfA[ks] = *(const short8*)(qpA + ks * 32);
      qfB[ks] = *(const short8*)(qpB + ks * 32);
    }
  }

  floatx4 o[8] = {};                  // O^T: col=q(l15), row=d(g*4+r)
  float m_s = -INFINITY;              // running max (RAW score units)
  float l_s = 0.f;

  auto stage = [&](int kt, int buf) {
#pragma unroll
    for (int ii = 0; ii < 4; ++ii) {          // K tile: 64 keys x 128 d
      int s = ii * 256 + tid;
      int r = s >> 4, j = (s & 15) ^ (r & 7);
      gload16(kbase + (size_t)(kt * 64 + r) * HEADD + j * 8, lK[buf] + s * 8);
    }
#pragma unroll
    for (int ii = 0; ii < 4; ++ii) {          // V^T tile: 128 d x 64 keys
      int s = ii * 256 + tid;
      int r = s >> 3, j = (s & 7) ^ (r & 7);
      gload16(vbase + (size_t)r * SEQ + kt * 64 + j * 8, lV[buf] + s * 8);
    }
  };

  auto compute = [&](const short8 (&qf)[4], int qw, int kt, int cur) {
    const int rel = qw - kt * 64;   // >= 0; < 64 only on the diagonal tile

    // S^T = K · Q^T : D col = q (l15), row = key (g*4+r), per nt key-16-block
    floatx4 sc4[4] = {};
    __builtin_amdgcn_s_setprio(1);
#pragma unroll
    for (int nt = 0; nt < 4; ++nt) {
      if (nt * 16 > rel + 15) continue;       // fully-masked key block (uniform)
#pragma unroll
      for (int ks = 0; ks < 4; ++ks) {
        short8 kf = *(const short8*)(lK[cur] + (nt * 16 + l15) * 128 + ((ks * 4 + g) ^ sw) * 8);
        sc4[nt] = __builtin_amdgcn_mfma_f32_16x16x32_bf16(kf, qf[ks], sc4[nt], 0, 0, 0);
      }
    }
    __builtin_amdgcn_s_setprio(0);

    const bool needmask = (kt * 64 + 63) > qw;  // wave-uniform
    float ps[4][4];
    float mx = -INFINITY;
#pragma unroll
    for (int nt = 0; nt < 4; ++nt)
#pragma unroll
      for (int r = 0; r < 4; ++r) {
        float v = sc4[nt][r];                 // RAW score (SC folded into exp)
        if (needmask) {
          int kg = kt * 64 + nt * 16 + g * 4 + r;
          if (kg > qw + l15) v = -INFINITY;
        }
        ps[nt][r] = v;
        mx = fmaxf(mx, v);
      }
    mx = fmaxf(mx, __shfl_xor(mx, 16));
    mx = fmaxf(mx, __shfl_xor(mx, 32));

    // defer-max: only rescale O when some row's max grew by > THR (rare)
    float mn;
    if (__all(mx <= m_s + THR)) {
      mn = m_s;
    } else {
      mn = fmaxf(m_s, mx);
      float alpha = __builtin_amdgcn_exp2f((m_s - mn) * SC);
      l_s *= alpha;
#pragma unroll
      for (int dt = 0; dt < 8; ++dt)
#pragma unroll
        for (int r = 0; r < 4; ++r) o[dt][r] *= alpha;
      m_s = mn;
    }
    const float mnSC = mn * SC;

    float rs = 0.f;
#pragma unroll
    for (int nt = 0; nt < 4; ++nt) {
      float e[4];
#pragma unroll
      for (int r = 0; r < 4; ++r) {
        e[r] = __builtin_amdgcn_exp2f(__builtin_fmaf(ps[nt][r], SC, -mnSC));
        rs += e[r];
      }
      uint2 pk;
      pk.x = cvt_pk_bf16(e[0], e[1]);
      pk.y = cvt_pk_bf16(e[2], e[3]);
      // row l15 (64 ushorts); 16B-granule (nt*2+(g>>1)) XOR-swizzled by l15&7
      *(uint2*)(pw + l15 * 64 + (((nt * 2 + (g >> 1)) ^ sw) * 8 + (g & 1) * 4)) = pk;
    }
    rs += __shfl_xor(rs, 16);
    rs += __shfl_xor(rs, 32);
    l_s += rs;

    // O^T += V^T · P^T   (A = V^T frag from lV, B = P^T frag from lP)
    __builtin_amdgcn_s_setprio(1);
#pragma unroll
    for (int ks = 0; ks < 2; ++ks) {
      if (kt * 64 + ks * 32 > qw + 15) continue;  // fully-masked (uniform)
      short8 bp = *(const short8*)(pw + l15 * 64 + ((ks * 4 + g) ^ sw) * 8);
#pragma unroll
      for (int dt = 0; dt < 8; ++dt) {
        short8 vf = *(const short8*)(lV[cur] + (dt * 16 + l15) * 64 + ((ks * 4 + g) ^ sw) * 8);
        o[dt] = __builtin_amdgcn_mfma_f32_16x16x32_bf16(vf, bp, o[dt], 0, 0, 0);
      }
    }
    __builtin_amdgcn_s_setprio(0);
  };

  auto epilogue = [&](int qw) {
    float inv = 1.f / l_s;
    int qg = qw + l15;
#pragma unroll
    for (int dt = 0; dt < 8; ++dt) {
      uint2 ov;
      ov.x = cvt_pk_bf16(o[dt][0] * inv, o[dt][1] * inv);
      ov.y = cvt_pk_bf16(o[dt][2] * inv, o[dt][3] * inv);
      *(uint2*)(Oa + (size_t)(b * SEQ + qg) * NQCOLS + h * HEADD + dt * 16 + g * 4) = ov;
    }
  };

  // ---- pipeline prologue ----
  stage(0, 0);
  asm volatile("s_waitcnt vmcnt(0)" ::: "memory");
  __builtin_amdgcn_s_barrier();

  // ---- phase A (long q-tile) ----
  for (int kt = 0; kt < nA; ++kt) {
    const int cur = kt & 1;
    if (kt + 1 < nA) stage(kt + 1, cur ^ 1);
    else             stage(0, cur ^ 1);        // prime phase B's tile 0
    compute(qfA, qwA, kt, cur);
    asm volatile("s_waitcnt vmcnt(0)" ::: "memory");
    __builtin_amdgcn_s_barrier();
  }
  epilogue(qwA);
#pragma unroll
  for (int dt = 0; dt < 8; ++dt) o[dt] = floatx4{0.f, 0.f, 0.f, 0.f};
  m_s = -INFINITY; l_s = 0.f;

  // ---- phase B (short q-tile); buffer parity continues from phase A ----
  for (int kt = 0; kt < nB; ++kt) {
    const int cur = (nA + kt) & 1;
    if (kt + 1 < nB) stage(kt + 1, cur ^ 1);
    compute(qfB, qwB, kt, cur);
    asm volatile("s_waitcnt vmcnt(0)" ::: "memory");
    __builtin_amdgcn_s_barrier();
  }
  epilogue(qwB);
}

extern "C" void kernel_launch(void* const* d_in, const int* in_sizes, int n_in,
                              void* d_out, int out_size, void* d_ws, size_t ws_size,
                              hipStream_t stream) {
  const float* x    = (const float*)d_in[0];
  const float* cosT = (const float*)d_in[1];
  const float* sinT = (const float*)d_in[2];
  const float* Wq   = (const float*)d_in[3];
  const float* Wkv  = (const float*)d_in[4];
  const float* Wo   = (const float*)d_in[5];

  char* ws = (char*)d_ws;
  // workspace layout (bytes)
  ushortT* x_bf   = (ushortT*)(ws + 0);          // 16777216
  ushortT* Wqkvt  = (ushortT*)(ws + 16777216);   // 12582912 (3072 x 2048 bf16)
  ushortT* Wot    = (ushortT*)(ws + 29360128);   //  8388608 (contiguous w/ Wqkvt)
  ushortT* QKVtmp = (ushortT*)(ws + 37748736);   // 25165824 (4096 x 3072 bf16)
  ushortT* Qr     = (ushortT*)(ws + 62914560);   // 16777216
  ushortT* Kr     = (ushortT*)(ws + 79691776);   //  4194304
  ushortT* Vt     = (ushortT*)(ws + 83886080);   //  4194304
  ushortT* Oattn  = QKVtmp;                      // alias; total 88080384

  // 1) cast + fused weight transposes (Wq|Wkv|Wo -> Wqkvt||Wot, one launch)
  cast_bf16_kernel<<<8192, 256, 0, stream>>>(x, x_bf, (MROWS * HDIM) / 4);
  transpose_cast3_kernel<<<dim3(160, 64), 256, 0, stream>>>(Wq, Wkv, Wo, Wqkvt);

  // 2) fused QKV projection: 128^2 3-slot-ring tiles, 768 blocks = exact 3/CU
  gemm_ring128_kernel<<<dim3(24, 32), 256, 0, stream>>>(x_bf, Wqkvt, QKVtmp,
                                                        MROWS, QKVCOLS, HDIM, 0);

  // 3) fused rope Q+K, then V relayout
  rope_qk_kernel<<<20480, 256, 0, stream>>>(QKVtmp, cosT, sinT, Qr, Kr);
  v_relayout_kernel<<<dim3(64, 4, 8), 256, 0, stream>>>(QKVtmp, Vt);

  // 4) attention: proven-best R8 kernel (512 blocks, paired q-tiles, 2/CU)
  attn_kernel<<<dim3(32, 16), 256, 0, stream>>>(Qr, Kr, Vt, Oattn);

  // 5) output projection: 128^2 3-slot-ring tiles, 512 blocks = 2/CU
  gemm_ring128_kernel<<<dim3(16, 32), 256, 0, stream>>>(Oattn, Wot, d_out,
                                                        MROWS, HDIM, NQCOLS, 1);
}